// Round 14
// baseline (755.814 us; speedup 1.0000x reference)
//
#include <hip/hip_runtime.h>

typedef __attribute__((ext_vector_type(8))) short bf16x8;
typedef __attribute__((ext_vector_type(4))) short bf16x4;
typedef __attribute__((ext_vector_type(4))) float f32x4;

__device__ __forceinline__ float bf2f(ushort u) {
  union { unsigned int i; float f; } v; v.i = ((unsigned int)u) << 16; return v.f;
}
__device__ __forceinline__ ushort f2bf(float f) {
  union { float f; unsigned int i; } v; v.f = f;
  unsigned int x = v.i;
  unsigned int r = (x + 0x7fffu + ((x >> 16) & 1u)) >> 16;
  return (ushort)r;
}

// async global->LDS, 16B per lane; LDS dest wave-uniform base (+lane*16 implicit)
__device__ __forceinline__ void gload_lds16(const ushort* g, ushort* l) {
  __builtin_amdgcn_global_load_lds((const __attribute__((address_space(1))) void*)g,
                                   (__attribute__((address_space(3))) void*)l, 16, 0, 0);
}

// ---------------------------------------------------------------- utilities
__global__ void zero_f32(float* p, int n) {
  int i = blockIdx.x * 256 + threadIdx.x;
  if (i < n) p[i] = 0.f;
}

// Pack W[co][ci][ky][kx] (fp32) -> Wp[tap][cic][cf][lane][8] (bf16)  (r2 layout)
__global__ void pack_w(const float* __restrict__ W, ushort* __restrict__ Wp, int Cin) {
  int ncic = Cin >> 5;
  int total = 9 * ncic * 8 * 64 * 8;
  for (int idx = blockIdx.x * 256 + threadIdx.x; idx < total; idx += gridDim.x * 256) {
    int j = idx & 7;
    int l = (idx >> 3) & 63;
    int cf = (idx >> 9) & 7;
    int rest = idx >> 12;
    int cic = rest % ncic;
    int tap = rest / ncic;
    int co = cf * 16 + (l & 15);
    int ci = cic * 32 + ((l >> 4) * 8) + j;
    int ky = tap / 3, kx = tap % 3;
    Wp[idx] = f2bf(W[((co * Cin + ci) * 3 + ky) * 3 + kx]);
  }
}

// NCHW fp32 [8][64][65536] -> NHWC bf16 [8][65536][64]
__global__ __launch_bounds__(256)
void nchw2nhwc(const float* __restrict__ in, ushort* __restrict__ out) {
  const int n  = blockIdx.y;
  const int p0 = blockIdx.x << 6;
  const int tid = threadIdx.x;
  __shared__ ushort t[64 * 72];
  {
    int c  = tid >> 2;
    int pq = (tid & 3) << 4;
    const float* ip = in + (((size_t)(n * 64 + c)) << 16) + p0 + pq;
#pragma unroll
    for (int k = 0; k < 4; ++k) {
      float4 f = *(const float4*)(ip + k * 4);
      int p = pq + k * 4;
      t[(p + 0) * 72 + c] = f2bf(f.x);
      t[(p + 1) * 72 + c] = f2bf(f.y);
      t[(p + 2) * 72 + c] = f2bf(f.z);
      t[(p + 3) * 72 + c] = f2bf(f.w);
    }
  }
  __syncthreads();
#pragma unroll
  for (int k = 0; k < 2; ++k) {
    int id = k * 256 + tid;
    int cj = id & 7, p = id >> 3;
    bf16x8 v = *(const bf16x8*)&t[p * 72 + cj * 8];
    *(bf16x8*)(out + ((((size_t)n << 16) + p0 + p) << 6) + cj * 8) = v;
  }
}

__device__ __forceinline__ bf16x8 bnrelu8(bf16x8 v, const float* __restrict__ coef, int c0) {
  float4 a0 = *(const float4*)(coef + c0);
  float4 a1 = *(const float4*)(coef + c0 + 4);
  float4 b0 = *(const float4*)(coef + 128 + c0);
  float4 b1 = *(const float4*)(coef + 128 + c0 + 4);
  bf16x8 r;
  r[0] = (short)f2bf(fmaxf(a0.x * bf2f((ushort)v[0]) + b0.x, 0.f));
  r[1] = (short)f2bf(fmaxf(a0.y * bf2f((ushort)v[1]) + b0.y, 0.f));
  r[2] = (short)f2bf(fmaxf(a0.z * bf2f((ushort)v[2]) + b0.z, 0.f));
  r[3] = (short)f2bf(fmaxf(a0.w * bf2f((ushort)v[3]) + b0.w, 0.f));
  r[4] = (short)f2bf(fmaxf(a1.x * bf2f((ushort)v[4]) + b1.x, 0.f));
  r[5] = (short)f2bf(fmaxf(a1.y * bf2f((ushort)v[5]) + b1.y, 0.f));
  r[6] = (short)f2bf(fmaxf(a1.z * bf2f((ushort)v[6]) + b1.z, 0.f));
  r[7] = (short)f2bf(fmaxf(a1.w * bf2f((ushort)v[7]) + b1.w, 0.f));
  return r;
}

// ---------------------------------------------------------------- y-persistent conv (Cin <= 128)
// Block owns a 16-row column (8 steps x 2 rows); LDS holds the FULL-DEPTH
// 4-row halo (4 planes x 66 xt x CIP=136 ci). Per step only 2 NEW rows are
// staged (steady staging -47%); per-wave inner loop is r2's verbatim
// (2 A-loads : 8 B-reads : 16 MFMA per tap). Epilogue reuses the retired
// row-plane as its transpose buffer.
template<int MODE, int NCIC>
__global__ __launch_bounds__(256)
void conv_yp(const ushort* __restrict__ src, const ushort* __restrict__ Wp,
             const float* __restrict__ bias, const float* __restrict__ coef,
             ushort* __restrict__ out, float* __restrict__ sSum, float* __restrict__ sSsq,
             int H, int W)
{
  constexpr int Cin = NCIC * 32;
  constexpr int CIP = 136;                 // padded ci stride (16B aligned, bank-spread)
  constexpr int PLANE = 66 * CIP;          // 8976 elems per row-plane
  const int x0 = blockIdx.x << 6;
  const int ysBase = blockIdx.y << 4;      // 16 output rows per block
  const int n  = blockIdx.z;
  const int tid = threadIdx.x;
  const int wv = tid >> 6, l = tid & 63, l15 = l & 15, l4 = l >> 4;

  __shared__ __align__(16) ushort smem[4 * PLANE];   // 71808 B

  const size_t HW = (size_t)H * W;
  const ushort* srcn = src + (size_t)n * HW * Cin;

  auto STAGE2 = [&](int r0) {   // stage absolute rows r0, r0+1 (all channels)
    constexpr int NCJ = NCIC * 4;
    constexpr int NCH = 2 * 66 * NCJ;
    for (int i = tid; i < NCH; i += 256) {
      int cj = i & (NCJ - 1);
      int t  = i / NCJ;
      int xt = t % 66;
      int r  = t / 66;
      int ry = r0 + r;
      int gx = x0 + xt - 1;
      bf16x8 v = {};
      if ((unsigned)ry < (unsigned)H && (unsigned)gx < (unsigned)W) {
        v = *(const bf16x8*)(srcn + ((size_t)ry * W + gx) * Cin + (cj << 3));
        if (MODE == 1) v = bnrelu8(v, coef, cj << 3);
      }
      *(bf16x8*)&smem[(ry & 3) * PLANE + xt * CIP + (cj << 3)] = v;
    }
  };

  STAGE2(ysBase - 1);
  STAGE2(ysBase + 1);
  __syncthreads();

  float sm[2][4] = {{0.f}}, sq[2][4] = {{0.f}};
  const int cb = (wv << 5) + (l4 << 2);
  const int rep = (int)((blockIdx.z * gridDim.y + blockIdx.y) * gridDim.x + blockIdx.x) & 31;

  for (int step = 0; step < 8; ++step) {
    const int ys = ysBase + (step << 1);

    f32x4 acc[2][2][4];
#pragma unroll
    for (int yr = 0; yr < 2; ++yr)
#pragma unroll
      for (int f = 0; f < 2; ++f)
#pragma unroll
        for (int xf = 0; xf < 4; ++xf) acc[yr][f][xf] = (f32x4){0.f, 0.f, 0.f, 0.f};

    for (int cic = 0; cic < NCIC; ++cic) {
#pragma unroll
      for (int tap = 0; tap < 9; ++tap) {
        const int ky = tap / 3, kx = tap % 3;
        bf16x8 afr[2];
#pragma unroll
        for (int f = 0; f < 2; ++f) {
          const int cf = (wv << 1) | f;
          afr[f] = *(const bf16x8*)(Wp + (((size_t)(tap * NCIC + cic) * 8 + cf) * 64 + l) * 8);
        }
        bf16x8 bfr[2][4];
#pragma unroll
        for (int yr = 0; yr < 2; ++yr)
#pragma unroll
          for (int xf = 0; xf < 4; ++xf) {
            int aRow = ys + yr - 1 + ky;
            bfr[yr][xf] = *(const bf16x8*)&smem[(aRow & 3) * PLANE +
                                               ((xf << 4) + l15 + kx) * CIP +
                                               (cic << 5) + (l4 << 3)];
          }
#pragma unroll
        for (int f = 0; f < 2; ++f)
#pragma unroll
          for (int yr = 0; yr < 2; ++yr)
#pragma unroll
            for (int xf = 0; xf < 4; ++xf)
              acc[yr][f][xf] = __builtin_amdgcn_mfma_f32_16x16x32_bf16(afr[f], bfr[yr][xf], acc[yr][f][xf], 0, 0, 0);
      }
    }

    __syncthreads();
    // epilogue: reuse the retired row-plane ((ys-1)&3) as [x64][co 136] buffer
    ushort* eps = &smem[((ys - 1) & 3) * PLANE];
    for (int yr = 0; yr < 2; ++yr) {
      if (yr) __syncthreads();
#pragma unroll
      for (int f = 0; f < 2; ++f) {
        const int cf = cb + (f << 4);
        float4 bv = *(const float4*)(bias + cf);
#pragma unroll
        for (int xf = 0; xf < 4; ++xf) {
          float v0 = acc[yr][f][xf][0] + bv.x;
          float v1 = acc[yr][f][xf][1] + bv.y;
          float v2 = acc[yr][f][xf][2] + bv.z;
          float v3 = acc[yr][f][xf][3] + bv.w;
          sm[f][0] += v0; sq[f][0] += v0 * v0;
          sm[f][1] += v1; sq[f][1] += v1 * v1;
          sm[f][2] += v2; sq[f][2] += v2 * v2;
          sm[f][3] += v3; sq[f][3] += v3 * v3;
          bf16x4 u;
          u[0] = (short)f2bf(v0); u[1] = (short)f2bf(v1);
          u[2] = (short)f2bf(v2); u[3] = (short)f2bf(v3);
          *(bf16x4*)&eps[((xf << 4) + l15) * 136 + cf] = u;
        }
      }
      __syncthreads();
      {
        const int xx = tid >> 2, c0 = (tid & 3) << 5;
        ushort* op = out + ((size_t)n * HW + (size_t)(ys + yr) * W + x0 + xx) * 128 + c0;
#pragma unroll
        for (int k = 0; k < 4; ++k)
          *(bf16x8*)(op + (k << 3)) = *(const bf16x8*)&eps[xx * 136 + c0 + (k << 3)];
      }
    }
    __syncthreads();
    if (step < 7) {
      STAGE2(ys + 3);     // refills the two retired planes
      __syncthreads();
    }
  }

#pragma unroll
  for (int f = 0; f < 2; ++f)
#pragma unroll
    for (int j = 0; j < 4; ++j) {
      float s = sm[f][j], q = sq[f][j];
#pragma unroll
      for (int o = 1; o < 16; o <<= 1) { s += __shfl_xor(s, o); q += __shfl_xor(q, o); }
      if (l15 == 0) {
        int co = cb + (f << 4) + j;
        atomicAdd(&sSum[rep * 128 + co], s);
        atomicAdd(&sSsq[rep * 128 + co], q);
      }
    }
}

// ---------------------------------------------------------------- conv (DMA-staged, for Cin=512)
__global__ __launch_bounds__(256)
void conv_dma(const ushort* __restrict__ src, const ushort* __restrict__ Wp,
              const float* __restrict__ bias,
              ushort* __restrict__ out, float* __restrict__ sSum, float* __restrict__ sSsq,
              int Cin, int H, int W)
{
  const int ncic = Cin >> 5;
  const int x0 = blockIdx.x << 6;
  const int y0 = blockIdx.y << 1;
  const int n  = blockIdx.z;
  const int tid = threadIdx.x;
  const int wv = tid >> 6, l = tid & 63, l15 = l & 15, l4 = l >> 4;

  __shared__ __align__(16) ushort smem[2 * 8448];

  const size_t HW = (size_t)H * W;
  const ushort* srcn = src + (size_t)n * HW * Cin;

  int off[5];
#pragma unroll
  for (int it = 0; it < 5; ++it) {
    int i = it * 256 + tid;
    int cj = i & 3, p = i >> 2;
    int row = p / 66, xt = p - row * 66;
    int ry = y0 + row - 1, gx = x0 + xt - 1;
    bool ok = (i < 1056) && ((unsigned)ry < (unsigned)H) && ((unsigned)gx < (unsigned)W);
    off[it] = ok ? (int)((ry * W + gx) * Cin + (cj << 3)) : -1;
  }

  if (x0 == 0 || x0 + 64 >= W || y0 == 0 || y0 + 2 >= H) {
    for (int k = tid; k < 2112; k += 256) *(bf16x8*)&smem[k << 3] = (bf16x8){};
  }
  __syncthreads();

  f32x4 acc[2][2][4];
#pragma unroll
  for (int yr = 0; yr < 2; ++yr)
#pragma unroll
    for (int f = 0; f < 2; ++f)
#pragma unroll
      for (int xf = 0; xf < 4; ++xf) acc[yr][f][xf] = (f32x4){0.f, 0.f, 0.f, 0.f};

  auto STAGE = [&](ushort* buf, int cic) {
    const int coff = cic << 5;
#pragma unroll
    for (int it = 0; it < 5; ++it) {
      ushort* ldst = buf + ((it < 4 ? (it * 256 + (wv << 6)) : 1024) << 3);
      if (off[it] >= 0)
        gload_lds16(srcn + off[it] + coff, ldst);
    }
  };

  auto COMPUTE = [&](const ushort* buf, int cic) {
#pragma unroll
    for (int tap = 0; tap < 9; ++tap) {
      const int ky = tap / 3, kx = tap % 3;
      bf16x8 afr[2];
#pragma unroll
      for (int f = 0; f < 2; ++f) {
        const int cf = (wv << 1) | f;
        afr[f] = *(const bf16x8*)(Wp + (((size_t)(tap * ncic + cic) * 8 + cf) * 64 + l) * 8);
      }
      bf16x8 bfr[2][4];
#pragma unroll
      for (int yr = 0; yr < 2; ++yr)
#pragma unroll
        for (int xf = 0; xf < 4; ++xf) {
          int row = yr + ky;
          int xt = (xf << 4) + l15 + kx;
          bfr[yr][xf] = *(const bf16x8*)&buf[((((row * 66 + xt) << 2) | l4)) << 3];
        }
#pragma unroll
      for (int f = 0; f < 2; ++f)
#pragma unroll
        for (int yr = 0; yr < 2; ++yr)
#pragma unroll
          for (int xf = 0; xf < 4; ++xf)
            acc[yr][f][xf] = __builtin_amdgcn_mfma_f32_16x16x32_bf16(afr[f], bfr[yr][xf], acc[yr][f][xf], 0, 0, 0);
    }
  };

  STAGE(smem, 0);
  __syncthreads();

  int cur = 0;
  for (int cic = 0; cic < ncic; ++cic) {
    if (cic + 1 < ncic) STAGE(smem + (cur ^ 1) * 8448, cic + 1);
    COMPUTE(smem + cur * 8448, cic);
    __syncthreads();
    cur ^= 1;
  }

  float sm[2][4] = {{0.f}}, sq[2][4] = {{0.f}};
  ushort* eps = smem;
  const int cb = (wv << 5) + (l4 << 2);
  for (int yr = 0; yr < 2; ++yr) {
    __syncthreads();
#pragma unroll
    for (int f = 0; f < 2; ++f) {
      const int cf = cb + (f << 4);
      float4 bv = *(const float4*)(bias + cf);
#pragma unroll
      for (int xf = 0; xf < 4; ++xf) {
        float v0 = acc[yr][f][xf][0] + bv.x;
        float v1 = acc[yr][f][xf][1] + bv.y;
        float v2 = acc[yr][f][xf][2] + bv.z;
        float v3 = acc[yr][f][xf][3] + bv.w;
        sm[f][0] += v0; sq[f][0] += v0 * v0;
        sm[f][1] += v1; sq[f][1] += v1 * v1;
        sm[f][2] += v2; sq[f][2] += v2 * v2;
        sm[f][3] += v3; sq[f][3] += v3 * v3;
        bf16x4 u;
        u[0] = (short)f2bf(v0); u[1] = (short)f2bf(v1);
        u[2] = (short)f2bf(v2); u[3] = (short)f2bf(v3);
        *(bf16x4*)&eps[((xf << 4) + l15) * 136 + cf] = u;
      }
    }
    __syncthreads();
    {
      const int xx = tid >> 2, c0 = (tid & 3) << 5;
      ushort* op = out + ((size_t)n * HW + (size_t)(y0 + yr) * W + x0 + xx) * 128 + c0;
#pragma unroll
      for (int k = 0; k < 4; ++k)
        *(bf16x8*)(op + (k << 3)) = *(const bf16x8*)&eps[xx * 136 + c0 + (k << 3)];
    }
  }

  const int rep = (int)((blockIdx.z * gridDim.y + blockIdx.y) * gridDim.x + blockIdx.x) & 31;
#pragma unroll
  for (int f = 0; f < 2; ++f)
#pragma unroll
    for (int j = 0; j < 4; ++j) {
      float s = sm[f][j], q = sq[f][j];
#pragma unroll
      for (int o = 1; o < 16; o <<= 1) { s += __shfl_xor(s, o); q += __shfl_xor(q, o); }
      if (l15 == 0) {
        int co = cb + (f << 4) + j;
        atomicAdd(&sSum[rep * 128 + co], s);
        atomicAdd(&sSsq[rep * 128 + co], q);
      }
    }
}

// ---------------------------------------------------------------- BN finalize
__global__ void bn_finalize(const float* __restrict__ sSum, const float* __restrict__ sSsq,
                            const float* __restrict__ g, const float* __restrict__ be,
                            float* __restrict__ coef, float invN)
{
  int c = threadIdx.x;  // 128
  float S = 0.f, Q = 0.f;
  for (int r = 0; r < 32; ++r) { S += sSum[r * 128 + c]; Q += sSsq[r * 128 + c]; }
  float m = S * invN;
  float v = Q * invN - m * m;
  float a = g[c] / sqrtf(v + 1e-5f);
  coef[c] = a;
  coef[128 + c] = be[c] - m * a;
}

// ---------------------------------------------------------------- fused bn_relu + skip out (NCHW fp32) + DWT (NHWC bf16)
__global__ __launch_bounds__(256)
void skip_dwt2(const ushort* __restrict__ skipRaw, const float* __restrict__ coef,
               float* __restrict__ outSkip, ushort* __restrict__ dwt)
{
  const int x0 = blockIdx.x << 6;
  const int oy = blockIdx.y;
  const int n  = blockIdx.z >> 2;
  const int ct = blockIdx.z & 3;
  const int y0 = oy << 1;
  const int tid = threadIdx.x;
  __shared__ float t32[32 * 2 * 68];

#pragma unroll
  for (int it = 0; it < 2; ++it) {
    int i = it * 256 + tid;
    int cj = i & 3, x = (i >> 2) & 63, r = i >> 8;
    int c0 = (ct << 5) + (cj << 3);
    bf16x8 v = *(const bf16x8*)(skipRaw + (((size_t)n << 16) + (size_t)(y0 + r) * 256 + x0 + x) * 128 + c0);
    float4 a0 = *(const float4*)(coef + c0);
    float4 a1 = *(const float4*)(coef + c0 + 4);
    float4 b0 = *(const float4*)(coef + 128 + c0);
    float4 b1 = *(const float4*)(coef + 128 + c0 + 4);
    float av[8] = {a0.x, a0.y, a0.z, a0.w, a1.x, a1.y, a1.z, a1.w};
    float bv[8] = {b0.x, b0.y, b0.z, b0.w, b1.x, b1.y, b1.z, b1.w};
    int cl = cj << 3;
#pragma unroll
    for (int k = 0; k < 8; ++k)
      t32[((cl + k) * 2 + r) * 68 + x] = fmaxf(av[k] * bf2f((ushort)v[k]) + bv[k], 0.f);
  }
  __syncthreads();

  {
    int c = tid >> 3, x8 = (tid & 7) << 3;
    float* op = outSkip + (((size_t)(n * 128 + (ct << 5) + c)) << 16) + (size_t)y0 * 256 + x0 + x8;
#pragma unroll
    for (int r = 0; r < 2; ++r) {
      float4 r0 = *(const float4*)&t32[(c * 2 + r) * 68 + x8];
      float4 r1 = *(const float4*)&t32[(c * 2 + r) * 68 + x8 + 4];
      *(float4*)(op + (size_t)r * 256) = r0;
      *(float4*)(op + (size_t)r * 256 + 4) = r1;
    }
  }

  if (tid < 128) {
    int cj = tid & 3, ox = tid >> 2;
    int cl = cj << 3;
    bf16x8 oA, oH, oV, oD;
#pragma unroll
    for (int k = 0; k < 8; ++k) {
      int c = cl + k;
      float p00 = t32[(c * 2 + 0) * 68 + 2 * ox];
      float p01 = t32[(c * 2 + 0) * 68 + 2 * ox + 1];
      float p10 = t32[(c * 2 + 1) * 68 + 2 * ox];
      float p11 = t32[(c * 2 + 1) * 68 + 2 * ox + 1];
      oA[k] = (short)f2bf((p00 + p01 + p10 + p11) * 0.5f);
      oH[k] = (short)f2bf((p00 + p01 - p10 - p11) * 0.5f);
      oV[k] = (short)f2bf((p00 - p01 + p10 - p11) * 0.5f);
      oD[k] = (short)f2bf((p00 - p01 - p10 + p11) * 0.5f);
    }
    size_t db = ((size_t)n * 16384 + (size_t)oy * 128 + (x0 >> 1) + ox) * 512 + (ct << 5) + cl;
    *(bf16x8*)(dwt + db)       = oA;
    *(bf16x8*)(dwt + db + 128) = oH;
    *(bf16x8*)(dwt + db + 256) = oV;
    *(bf16x8*)(dwt + db + 384) = oD;
  }
}

// ---------------------------------------------------------------- bn_relu + NHWC->NCHW fp32 out
__global__ __launch_bounds__(256)
void bn_transpose_out(const ushort* __restrict__ src, const float* __restrict__ coef,
                      float* __restrict__ dst, int H, int W)
{
  const int n  = blockIdx.z >> 2;
  const int cc = blockIdx.z & 3;
  const int x0 = blockIdx.x << 6;
  const int y  = blockIdx.y;
  const int tid = threadIdx.x;
  __shared__ float t[32 * 68];
  const size_t HW = (size_t)H * W;
  {
    int p = tid >> 2, cj = tid & 3;
    int c0 = (cc << 5) + (cj << 3);
    bf16x8 v = *(const bf16x8*)(src + ((size_t)n * HW + (size_t)y * W + x0 + p) * 128 + c0);
    float4 a0 = *(const float4*)(coef + c0);
    float4 a1 = *(const float4*)(coef + c0 + 4);
    float4 b0 = *(const float4*)(coef + 128 + c0);
    float4 b1 = *(const float4*)(coef + 128 + c0 + 4);
    int cl = cj << 3;
    t[(cl + 0) * 68 + p] = fmaxf(a0.x * bf2f((ushort)v[0]) + b0.x, 0.f);
    t[(cl + 1) * 68 + p] = fmaxf(a0.y * bf2f((ushort)v[1]) + b0.y, 0.f);
    t[(cl + 2) * 68 + p] = fmaxf(a0.z * bf2f((ushort)v[2]) + b0.z, 0.f);
    t[(cl + 3) * 68 + p] = fmaxf(a0.w * bf2f((ushort)v[3]) + b0.w, 0.f);
    t[(cl + 4) * 68 + p] = fmaxf(a1.x * bf2f((ushort)v[4]) + b1.x, 0.f);
    t[(cl + 5) * 68 + p] = fmaxf(a1.y * bf2f((ushort)v[5]) + b1.y, 0.f);
    t[(cl + 6) * 68 + p] = fmaxf(a1.z * bf2f((ushort)v[6]) + b1.z, 0.f);
    t[(cl + 7) * 68 + p] = fmaxf(a1.w * bf2f((ushort)v[7]) + b1.w, 0.f);
  }
  __syncthreads();
  {
    int c = tid >> 3, x8 = (tid & 7) << 3;
    float4 r0 = *(const float4*)&t[c * 68 + x8];
    float4 r1 = *(const float4*)&t[c * 68 + x8 + 4];
    float* op = dst + ((size_t)(n * 128 + (cc << 5) + c)) * HW + (size_t)y * W + x0 + x8;
    *(float4*)op = r0;
    *(float4*)(op + 4) = r1;
  }
}

// ---------------------------------------------------------------- launch
extern "C" void kernel_launch(void* const* d_in, const int* in_sizes, int n_in,
                              void* d_out, int out_size, void* d_ws, size_t ws_size,
                              hipStream_t stream)
{
  const float* input = (const float*)d_in[0];
  const float* W1  = (const float*)d_in[1];
  const float* b1  = (const float*)d_in[2];
  const float* g1  = (const float*)d_in[3];
  const float* be1 = (const float*)d_in[4];
  const float* W2  = (const float*)d_in[5];
  const float* b2  = (const float*)d_in[6];
  const float* g2  = (const float*)d_in[7];
  const float* be2 = (const float*)d_in[8];
  const float* W3  = (const float*)d_in[9];
  const float* b3  = (const float*)d_in[10];
  const float* g3  = (const float*)d_in[11];
  const float* be3 = (const float*)d_in[12];

  char* ws = (char*)d_ws;
  ushort* h_raw    = (ushort*)(ws + 0);            // NHWC [8][65536][128]
  ushort* skip_raw = (ushort*)(ws + 134217728);    // NHWC [8][65536][128]
  ushort* dwt      = (ushort*)(ws + 268435456);    // NHWC [8][16384][512]
  ushort* in_nhwc  = (ushort*)(ws + 268435456);    // NHWC [8][65536][64] (aliased w/ dwt; dead before dwt written)
  ushort* raw3     = (ushort*)(ws + 402653184);    // NHWC [8][16384][128]
  float*  stats    = (float*)(ws + 436207616);
  float*  s1 = stats,          *q1 = stats + 4096;
  float*  s2 = stats + 8192,   *q2 = stats + 12288;
  float*  s3 = stats + 16384,  *q3 = stats + 20480;
  float*  coef = (float*)(ws + 436305920);
  float*  c1 = coef, *c2 = coef + 256, *c3 = coef + 512;
  ushort* Wp1 = (ushort*)(ws + 436308992);
  ushort* Wp2 = (ushort*)(ws + 436456448);
  ushort* Wp3 = (ushort*)(ws + 436751360);

  zero_f32<<<96, 256, 0, stream>>>(stats, 24576);
  pack_w<<<288, 256, 0, stream>>>(W1, Wp1, 64);
  pack_w<<<576, 256, 0, stream>>>(W2, Wp2, 128);
  pack_w<<<2304, 256, 0, stream>>>(W3, Wp3, 512);
  nchw2nhwc<<<dim3(1024, 8), 256, 0, stream>>>(input, in_nhwc);

  conv_yp<0, 2><<<dim3(4, 16, 8), 256, 0, stream>>>(in_nhwc, Wp1, b1, nullptr,
                                                    h_raw, s1, q1, 256, 256);
  bn_finalize<<<1, 128, 0, stream>>>(s1, q1, g1, be1, c1, 1.f / 524288.f);

  conv_yp<1, 4><<<dim3(4, 16, 8), 256, 0, stream>>>(h_raw, Wp2, b2, c1,
                                                    skip_raw, s2, q2, 256, 256);
  bn_finalize<<<1, 128, 0, stream>>>(s2, q2, g2, be2, c2, 1.f / 524288.f);

  skip_dwt2<<<dim3(4, 128, 32), 256, 0, stream>>>(skip_raw, c2, (float*)d_out, dwt);

  conv_dma<<<dim3(2, 64, 8), 256, 0, stream>>>(dwt, Wp3, b3,
                                               raw3, s3, q3, 512, 128, 128);
  bn_finalize<<<1, 128, 0, stream>>>(s3, q3, g3, be3, c3, 1.f / 131072.f);

  bn_transpose_out<<<dim3(2, 128, 32), 256, 0, stream>>>(raw3, c3, (float*)d_out + 67108864, 128, 128);
}

// Round 15
// 696.009 us; speedup vs baseline: 1.0859x; 1.0859x over previous
//
#include <hip/hip_runtime.h>

typedef __attribute__((ext_vector_type(8))) short bf16x8;
typedef __attribute__((ext_vector_type(4))) short bf16x4;
typedef __attribute__((ext_vector_type(4))) float f32x4;

__device__ __forceinline__ float bf2f(ushort u) {
  union { unsigned int i; float f; } v; v.i = ((unsigned int)u) << 16; return v.f;
}
__device__ __forceinline__ ushort f2bf(float f) {
  union { float f; unsigned int i; } v; v.f = f;
  unsigned int x = v.i;
  unsigned int r = (x + 0x7fffu + ((x >> 16) & 1u)) >> 16;
  return (ushort)r;
}

// async global->LDS, 16B per lane; LDS dest wave-uniform base (+lane*16 implicit)
__device__ __forceinline__ void gload_lds16(const ushort* g, ushort* l) {
  __builtin_amdgcn_global_load_lds((const __attribute__((address_space(1))) void*)g,
                                   (__attribute__((address_space(3))) void*)l, 16, 0, 0);
}

// ---------------------------------------------------------------- utilities
__global__ void zero_f32(float* p, int n) {
  int i = blockIdx.x * 256 + threadIdx.x;
  if (i < n) p[i] = 0.f;
}

// Pack W[co][ci][ky][kx] (fp32) -> Wp[tap][cic][cf][lane][8] (bf16)  (r2 layout)
__global__ void pack_w(const float* __restrict__ W, ushort* __restrict__ Wp, int Cin) {
  int ncic = Cin >> 5;
  int total = 9 * ncic * 8 * 64 * 8;
  for (int idx = blockIdx.x * 256 + threadIdx.x; idx < total; idx += gridDim.x * 256) {
    int j = idx & 7;
    int l = (idx >> 3) & 63;
    int cf = (idx >> 9) & 7;
    int rest = idx >> 12;
    int cic = rest % ncic;
    int tap = rest / ncic;
    int co = cf * 16 + (l & 15);
    int ci = cic * 32 + ((l >> 4) * 8) + j;
    int ky = tap / 3, kx = tap % 3;
    Wp[idx] = f2bf(W[((co * Cin + ci) * 3 + ky) * 3 + kx]);
  }
}

// NCHW fp32 [8][64][65536] -> NHWC bf16 [8][65536][64]
__global__ __launch_bounds__(256)
void nchw2nhwc(const float* __restrict__ in, ushort* __restrict__ out) {
  const int n  = blockIdx.y;
  const int p0 = blockIdx.x << 6;
  const int tid = threadIdx.x;
  __shared__ ushort t[64 * 72];
  {
    int c  = tid >> 2;
    int pq = (tid & 3) << 4;
    const float* ip = in + (((size_t)(n * 64 + c)) << 16) + p0 + pq;
#pragma unroll
    for (int k = 0; k < 4; ++k) {
      float4 f = *(const float4*)(ip + k * 4);
      int p = pq + k * 4;
      t[(p + 0) * 72 + c] = f2bf(f.x);
      t[(p + 1) * 72 + c] = f2bf(f.y);
      t[(p + 2) * 72 + c] = f2bf(f.z);
      t[(p + 3) * 72 + c] = f2bf(f.w);
    }
  }
  __syncthreads();
#pragma unroll
  for (int k = 0; k < 2; ++k) {
    int id = k * 256 + tid;
    int cj = id & 7, p = id >> 3;
    bf16x8 v = *(const bf16x8*)&t[p * 72 + cj * 8];
    *(bf16x8*)(out + ((((size_t)n << 16) + p0 + p) << 6) + cj * 8) = v;
  }
}

__device__ __forceinline__ bf16x8 bnrelu8(bf16x8 v, const float* __restrict__ coef, int c0) {
  float4 a0 = *(const float4*)(coef + c0);
  float4 a1 = *(const float4*)(coef + c0 + 4);
  float4 b0 = *(const float4*)(coef + 128 + c0);
  float4 b1 = *(const float4*)(coef + 128 + c0 + 4);
  bf16x8 r;
  r[0] = (short)f2bf(fmaxf(a0.x * bf2f((ushort)v[0]) + b0.x, 0.f));
  r[1] = (short)f2bf(fmaxf(a0.y * bf2f((ushort)v[1]) + b0.y, 0.f));
  r[2] = (short)f2bf(fmaxf(a0.z * bf2f((ushort)v[2]) + b0.z, 0.f));
  r[3] = (short)f2bf(fmaxf(a0.w * bf2f((ushort)v[3]) + b0.w, 0.f));
  r[4] = (short)f2bf(fmaxf(a1.x * bf2f((ushort)v[4]) + b1.x, 0.f));
  r[5] = (short)f2bf(fmaxf(a1.y * bf2f((ushort)v[5]) + b1.y, 0.f));
  r[6] = (short)f2bf(fmaxf(a1.z * bf2f((ushort)v[6]) + b1.z, 0.f));
  r[7] = (short)f2bf(fmaxf(a1.w * bf2f((ushort)v[7]) + b1.w, 0.f));
  return r;
}

// ---------------------------------------------------------------- conv (reg-staged, r2 verbatim)
// 256 thr = 4 waves; wave wv = cf-pair (32 co) x 64 px x both rows.
// Single LDS buffer, 2 barriers/cic; MODE 1 fuses relu(a*x+b) at staging.
template<int MODE>
__global__ __launch_bounds__(256)
void conv_reg(const ushort* __restrict__ src, const ushort* __restrict__ Wp,
              const float* __restrict__ bias, const float* __restrict__ coef,
              ushort* __restrict__ out, float* __restrict__ sSum, float* __restrict__ sSsq,
              int Cin, int H, int W)
{
  const int ncic = Cin >> 5;
  const int x0 = blockIdx.x << 6;
  const int y0 = blockIdx.y << 1;
  const int n  = blockIdx.z;
  const int tid = threadIdx.x;
  const int wv = tid >> 6, l = tid & 63, l15 = l & 15, l4 = l >> 4;

  __shared__ __align__(16) char smem[17408];
  ushort* lds = (ushort*)smem;   // staging: [row4][cj4][xt66] chunks
  ushort* eps = (ushort*)smem;   // epilogue: [x64][co 136]

  f32x4 acc[2][2][4];
#pragma unroll
  for (int yr = 0; yr < 2; ++yr)
#pragma unroll
    for (int f = 0; f < 2; ++f)
#pragma unroll
      for (int xf = 0; xf < 4; ++xf) acc[yr][f][xf] = (f32x4){0.f, 0.f, 0.f, 0.f};

  const size_t HW = (size_t)H * W;

  for (int cic = 0; cic < ncic; ++cic) {
    __syncthreads();
    for (int i = tid; i < 1056; i += 256) {
      int cj = i & 3;
      int t = i >> 2;
      int row = t / 66;
      int xt = t - row * 66;
      int ry = y0 + row - 1;
      int gx = x0 + xt - 1;
      bf16x8 v = {};
      if ((unsigned)ry < (unsigned)H && (unsigned)gx < (unsigned)W) {
        const ushort* p = src + ((size_t)n * HW + (size_t)ry * W + gx) * Cin + (cic << 5) + (cj << 3);
        v = *(const bf16x8*)p;
        if (MODE == 1) v = bnrelu8(v, coef, (cic << 5) + (cj << 3));
      }
      *(bf16x8*)&lds[(((row << 2) | cj) * 66 + xt) << 3] = v;
    }
    __syncthreads();

#pragma unroll
    for (int tap = 0; tap < 9; ++tap) {
      const int ky = tap / 3, kx = tap % 3;
      bf16x8 afr[2];
#pragma unroll
      for (int f = 0; f < 2; ++f) {
        const int cf = (wv << 1) | f;
        afr[f] = *(const bf16x8*)(Wp + (((size_t)(tap * ncic + cic) * 8 + cf) * 64 + l) * 8);
      }
      bf16x8 bfr[2][4];
#pragma unroll
      for (int yr = 0; yr < 2; ++yr)
#pragma unroll
        for (int xf = 0; xf < 4; ++xf) {
          int row = yr + ky;
          int xt = (xf << 4) + l15 + kx;
          bfr[yr][xf] = *(const bf16x8*)&lds[(((row << 2) | l4) * 66 + xt) << 3];
        }
#pragma unroll
      for (int f = 0; f < 2; ++f)
#pragma unroll
        for (int yr = 0; yr < 2; ++yr)
#pragma unroll
          for (int xf = 0; xf < 4; ++xf)
            acc[yr][f][xf] = __builtin_amdgcn_mfma_f32_16x16x32_bf16(afr[f], bfr[yr][xf], acc[yr][f][xf], 0, 0, 0);
    }
  }

  // epilogue
  float sm[2][4] = {{0.f}}, sq[2][4] = {{0.f}};
  const int cb = (wv << 5) + (l4 << 2);
  for (int yr = 0; yr < 2; ++yr) {
    __syncthreads();
#pragma unroll
    for (int f = 0; f < 2; ++f) {
      const int cf = cb + (f << 4);
      float4 bv = *(const float4*)(bias + cf);
#pragma unroll
      for (int xf = 0; xf < 4; ++xf) {
        float v0 = acc[yr][f][xf][0] + bv.x;
        float v1 = acc[yr][f][xf][1] + bv.y;
        float v2 = acc[yr][f][xf][2] + bv.z;
        float v3 = acc[yr][f][xf][3] + bv.w;
        sm[f][0] += v0; sq[f][0] += v0 * v0;
        sm[f][1] += v1; sq[f][1] += v1 * v1;
        sm[f][2] += v2; sq[f][2] += v2 * v2;
        sm[f][3] += v3; sq[f][3] += v3 * v3;
        bf16x4 u;
        u[0] = (short)f2bf(v0); u[1] = (short)f2bf(v1);
        u[2] = (short)f2bf(v2); u[3] = (short)f2bf(v3);
        *(bf16x4*)&eps[((xf << 4) + l15) * 136 + cf] = u;
      }
    }
    __syncthreads();
    {
      const int xx = tid >> 2, c0 = (tid & 3) << 5;
      ushort* op = out + ((size_t)n * HW + (size_t)(y0 + yr) * W + x0 + xx) * 128 + c0;
#pragma unroll
      for (int k = 0; k < 4; ++k)
        *(bf16x8*)(op + (k << 3)) = *(const bf16x8*)&eps[xx * 136 + c0 + (k << 3)];
    }
  }

  const int rep = (int)((blockIdx.z * gridDim.y + blockIdx.y) * gridDim.x + blockIdx.x) & 31;
#pragma unroll
  for (int f = 0; f < 2; ++f)
#pragma unroll
    for (int j = 0; j < 4; ++j) {
      float s = sm[f][j], q = sq[f][j];
#pragma unroll
      for (int o = 1; o < 16; o <<= 1) { s += __shfl_xor(s, o); q += __shfl_xor(q, o); }
      if (l15 == 0) {
        int co = cb + (f << 4) + j;
        atomicAdd(&sSum[rep * 128 + co], s);
        atomicAdd(&sSsq[rep * 128 + co], q);
      }
    }
}

// ---------------------------------------------------------------- conv (DMA-staged, MODE 0 only)
// Same wave tile/epilogue as conv_reg; staging via global_load_lds with
// LINEAR chunk layout [row][xt][cj] on BOTH sides: chunk i (cj=i&3, p=i>>2 ->
// row=p/66, xt=p%66) lands at LDS slot i, B-frag reads slot ((row*66+xt)<<2)|l4.
// Double-buffered, 1 barrier/cic.
__global__ __launch_bounds__(256)
void conv_dma(const ushort* __restrict__ src, const ushort* __restrict__ Wp,
              const float* __restrict__ bias,
              ushort* __restrict__ out, float* __restrict__ sSum, float* __restrict__ sSsq,
              int Cin, int H, int W)
{
  const int ncic = Cin >> 5;
  const int x0 = blockIdx.x << 6;
  const int y0 = blockIdx.y << 1;
  const int n  = blockIdx.z;
  const int tid = threadIdx.x;
  const int wv = tid >> 6, l = tid & 63, l15 = l & 15, l4 = l >> 4;

  __shared__ __align__(16) ushort smem[2 * 8448];   // 2 x 1056 chunks of 16B

  const size_t HW = (size_t)H * W;
  const ushort* srcn = src + (size_t)n * HW * Cin;

  int off[5];
#pragma unroll
  for (int it = 0; it < 5; ++it) {
    int i = it * 256 + tid;
    int cj = i & 3, p = i >> 2;
    int row = p / 66, xt = p - row * 66;
    int ry = y0 + row - 1, gx = x0 + xt - 1;
    bool ok = (i < 1056) && ((unsigned)ry < (unsigned)H) && ((unsigned)gx < (unsigned)W);
    off[it] = ok ? (int)((ry * W + gx) * Cin + (cj << 3)) : -1;
  }

  // zero halo chunks once (border blocks only; OOB slots never DMA-written)
  if (x0 == 0 || x0 + 64 >= W || y0 == 0 || y0 + 2 >= H) {
    for (int k = tid; k < 2112; k += 256) *(bf16x8*)&smem[k << 3] = (bf16x8){};
  }
  __syncthreads();

  f32x4 acc[2][2][4];
#pragma unroll
  for (int yr = 0; yr < 2; ++yr)
#pragma unroll
    for (int f = 0; f < 2; ++f)
#pragma unroll
      for (int xf = 0; xf < 4; ++xf) acc[yr][f][xf] = (f32x4){0.f, 0.f, 0.f, 0.f};

  auto STAGE = [&](ushort* buf, int cic) {
    const int coff = cic << 5;
#pragma unroll
    for (int it = 0; it < 5; ++it) {
      ushort* ldst = buf + ((it < 4 ? (it * 256 + (wv << 6)) : 1024) << 3);
      if (off[it] >= 0)
        gload_lds16(srcn + off[it] + coff, ldst);
    }
  };

  auto COMPUTE = [&](const ushort* buf, int cic) {
#pragma unroll
    for (int tap = 0; tap < 9; ++tap) {
      const int ky = tap / 3, kx = tap % 3;
      bf16x8 afr[2];
#pragma unroll
      for (int f = 0; f < 2; ++f) {
        const int cf = (wv << 1) | f;
        afr[f] = *(const bf16x8*)(Wp + (((size_t)(tap * ncic + cic) * 8 + cf) * 64 + l) * 8);
      }
      bf16x8 bfr[2][4];
#pragma unroll
      for (int yr = 0; yr < 2; ++yr)
#pragma unroll
        for (int xf = 0; xf < 4; ++xf) {
          int row = yr + ky;
          int xt = (xf << 4) + l15 + kx;
          bfr[yr][xf] = *(const bf16x8*)&buf[((((row * 66 + xt) << 2) | l4)) << 3];
        }
#pragma unroll
      for (int f = 0; f < 2; ++f)
#pragma unroll
        for (int yr = 0; yr < 2; ++yr)
#pragma unroll
          for (int xf = 0; xf < 4; ++xf)
            acc[yr][f][xf] = __builtin_amdgcn_mfma_f32_16x16x32_bf16(afr[f], bfr[yr][xf], acc[yr][f][xf], 0, 0, 0);
    }
  };

  STAGE(smem, 0);
  __syncthreads();

  int cur = 0;
  for (int cic = 0; cic < ncic; ++cic) {
    if (cic + 1 < ncic) STAGE(smem + (cur ^ 1) * 8448, cic + 1);
    COMPUTE(smem + cur * 8448, cic);
    __syncthreads();
    cur ^= 1;
  }

  // epilogue (same as conv_reg)
  float sm[2][4] = {{0.f}}, sq[2][4] = {{0.f}};
  ushort* eps = smem;
  const int cb = (wv << 5) + (l4 << 2);
  for (int yr = 0; yr < 2; ++yr) {
    __syncthreads();
#pragma unroll
    for (int f = 0; f < 2; ++f) {
      const int cf = cb + (f << 4);
      float4 bv = *(const float4*)(bias + cf);
#pragma unroll
      for (int xf = 0; xf < 4; ++xf) {
        float v0 = acc[yr][f][xf][0] + bv.x;
        float v1 = acc[yr][f][xf][1] + bv.y;
        float v2 = acc[yr][f][xf][2] + bv.z;
        float v3 = acc[yr][f][xf][3] + bv.w;
        sm[f][0] += v0; sq[f][0] += v0 * v0;
        sm[f][1] += v1; sq[f][1] += v1 * v1;
        sm[f][2] += v2; sq[f][2] += v2 * v2;
        sm[f][3] += v3; sq[f][3] += v3 * v3;
        bf16x4 u;
        u[0] = (short)f2bf(v0); u[1] = (short)f2bf(v1);
        u[2] = (short)f2bf(v2); u[3] = (short)f2bf(v3);
        *(bf16x4*)&eps[((xf << 4) + l15) * 136 + cf] = u;
      }
    }
    __syncthreads();
    {
      const int xx = tid >> 2, c0 = (tid & 3) << 5;
      ushort* op = out + ((size_t)n * HW + (size_t)(y0 + yr) * W + x0 + xx) * 128 + c0;
#pragma unroll
      for (int k = 0; k < 4; ++k)
        *(bf16x8*)(op + (k << 3)) = *(const bf16x8*)&eps[xx * 136 + c0 + (k << 3)];
    }
  }

  const int rep = (int)((blockIdx.z * gridDim.y + blockIdx.y) * gridDim.x + blockIdx.x) & 31;
#pragma unroll
  for (int f = 0; f < 2; ++f)
#pragma unroll
    for (int j = 0; j < 4; ++j) {
      float s = sm[f][j], q = sq[f][j];
#pragma unroll
      for (int o = 1; o < 16; o <<= 1) { s += __shfl_xor(s, o); q += __shfl_xor(q, o); }
      if (l15 == 0) {
        int co = cb + (f << 4) + j;
        atomicAdd(&sSum[rep * 128 + co], s);
        atomicAdd(&sSsq[rep * 128 + co], q);
      }
    }
}

// ---------------------------------------------------------------- BN finalize
__global__ void bn_finalize(const float* __restrict__ sSum, const float* __restrict__ sSsq,
                            const float* __restrict__ g, const float* __restrict__ be,
                            float* __restrict__ coef, float invN)
{
  int c = threadIdx.x;  // 128
  float S = 0.f, Q = 0.f;
  for (int r = 0; r < 32; ++r) { S += sSum[r * 128 + c]; Q += sSsq[r * 128 + c]; }
  float m = S * invN;
  float v = Q * invN - m * m;
  float a = g[c] / sqrtf(v + 1e-5f);
  coef[c] = a;
  coef[128 + c] = be[c] - m * a;
}

// ---------------------------------------------------------------- fused bn_relu + skip out (NCHW fp32) + DWT (NHWC bf16)
__global__ __launch_bounds__(256)
void skip_dwt2(const ushort* __restrict__ skipRaw, const float* __restrict__ coef,
               float* __restrict__ outSkip, ushort* __restrict__ dwt)
{
  const int x0 = blockIdx.x << 6;
  const int oy = blockIdx.y;
  const int n  = blockIdx.z >> 2;
  const int ct = blockIdx.z & 3;
  const int y0 = oy << 1;
  const int tid = threadIdx.x;
  __shared__ float t32[32 * 2 * 68];

#pragma unroll
  for (int it = 0; it < 2; ++it) {
    int i = it * 256 + tid;
    int cj = i & 3, x = (i >> 2) & 63, r = i >> 8;
    int c0 = (ct << 5) + (cj << 3);
    bf16x8 v = *(const bf16x8*)(skipRaw + (((size_t)n << 16) + (size_t)(y0 + r) * 256 + x0 + x) * 128 + c0);
    float4 a0 = *(const float4*)(coef + c0);
    float4 a1 = *(const float4*)(coef + c0 + 4);
    float4 b0 = *(const float4*)(coef + 128 + c0);
    float4 b1 = *(const float4*)(coef + 128 + c0 + 4);
    float av[8] = {a0.x, a0.y, a0.z, a0.w, a1.x, a1.y, a1.z, a1.w};
    float bv[8] = {b0.x, b0.y, b0.z, b0.w, b1.x, b1.y, b1.z, b1.w};
    int cl = cj << 3;
#pragma unroll
    for (int k = 0; k < 8; ++k)
      t32[((cl + k) * 2 + r) * 68 + x] = fmaxf(av[k] * bf2f((ushort)v[k]) + bv[k], 0.f);
  }
  __syncthreads();

  {
    int c = tid >> 3, x8 = (tid & 7) << 3;
    float* op = outSkip + (((size_t)(n * 128 + (ct << 5) + c)) << 16) + (size_t)y0 * 256 + x0 + x8;
#pragma unroll
    for (int r = 0; r < 2; ++r) {
      float4 r0 = *(const float4*)&t32[(c * 2 + r) * 68 + x8];
      float4 r1 = *(const float4*)&t32[(c * 2 + r) * 68 + x8 + 4];
      *(float4*)(op + (size_t)r * 256) = r0;
      *(float4*)(op + (size_t)r * 256 + 4) = r1;
    }
  }

  if (tid < 128) {
    int cj = tid & 3, ox = tid >> 2;
    int cl = cj << 3;
    bf16x8 oA, oH, oV, oD;
#pragma unroll
    for (int k = 0; k < 8; ++k) {
      int c = cl + k;
      float p00 = t32[(c * 2 + 0) * 68 + 2 * ox];
      float p01 = t32[(c * 2 + 0) * 68 + 2 * ox + 1];
      float p10 = t32[(c * 2 + 1) * 68 + 2 * ox];
      float p11 = t32[(c * 2 + 1) * 68 + 2 * ox + 1];
      oA[k] = (short)f2bf((p00 + p01 + p10 + p11) * 0.5f);
      oH[k] = (short)f2bf((p00 + p01 - p10 - p11) * 0.5f);
      oV[k] = (short)f2bf((p00 - p01 + p10 - p11) * 0.5f);
      oD[k] = (short)f2bf((p00 - p01 - p10 + p11) * 0.5f);
    }
    size_t db = ((size_t)n * 16384 + (size_t)oy * 128 + (x0 >> 1) + ox) * 512 + (ct << 5) + cl;
    *(bf16x8*)(dwt + db)       = oA;
    *(bf16x8*)(dwt + db + 128) = oH;
    *(bf16x8*)(dwt + db + 256) = oV;
    *(bf16x8*)(dwt + db + 384) = oD;
  }
}

// ---------------------------------------------------------------- bn_relu + NHWC->NCHW fp32 out
__global__ __launch_bounds__(256)
void bn_transpose_out(const ushort* __restrict__ src, const float* __restrict__ coef,
                      float* __restrict__ dst, int H, int W)
{
  const int n  = blockIdx.z >> 2;
  const int cc = blockIdx.z & 3;
  const int x0 = blockIdx.x << 6;
  const int y  = blockIdx.y;
  const int tid = threadIdx.x;
  __shared__ float t[32 * 68];
  const size_t HW = (size_t)H * W;
  {
    int p = tid >> 2, cj = tid & 3;
    int c0 = (cc << 5) + (cj << 3);
    bf16x8 v = *(const bf16x8*)(src + ((size_t)n * HW + (size_t)y * W + x0 + p) * 128 + c0);
    float4 a0 = *(const float4*)(coef + c0);
    float4 a1 = *(const float4*)(coef + c0 + 4);
    float4 b0 = *(const float4*)(coef + 128 + c0);
    float4 b1 = *(const float4*)(coef + 128 + c0 + 4);
    int cl = cj << 3;
    t[(cl + 0) * 68 + p] = fmaxf(a0.x * bf2f((ushort)v[0]) + b0.x, 0.f);
    t[(cl + 1) * 68 + p] = fmaxf(a0.y * bf2f((ushort)v[1]) + b0.y, 0.f);
    t[(cl + 2) * 68 + p] = fmaxf(a0.z * bf2f((ushort)v[2]) + b0.z, 0.f);
    t[(cl + 3) * 68 + p] = fmaxf(a0.w * bf2f((ushort)v[3]) + b0.w, 0.f);
    t[(cl + 4) * 68 + p] = fmaxf(a1.x * bf2f((ushort)v[4]) + b1.x, 0.f);
    t[(cl + 5) * 68 + p] = fmaxf(a1.y * bf2f((ushort)v[5]) + b1.y, 0.f);
    t[(cl + 6) * 68 + p] = fmaxf(a1.z * bf2f((ushort)v[6]) + b1.z, 0.f);
    t[(cl + 7) * 68 + p] = fmaxf(a1.w * bf2f((ushort)v[7]) + b1.w, 0.f);
  }
  __syncthreads();
  {
    int c = tid >> 3, x8 = (tid & 7) << 3;
    float4 r0 = *(const float4*)&t[c * 68 + x8];
    float4 r1 = *(const float4*)&t[c * 68 + x8 + 4];
    float* op = dst + ((size_t)(n * 128 + (cc << 5) + c)) * HW + (size_t)y * W + x0 + x8;
    *(float4*)op = r0;
    *(float4*)(op + 4) = r1;
  }
}

// ---------------------------------------------------------------- launch
extern "C" void kernel_launch(void* const* d_in, const int* in_sizes, int n_in,
                              void* d_out, int out_size, void* d_ws, size_t ws_size,
                              hipStream_t stream)
{
  const float* input = (const float*)d_in[0];
  const float* W1  = (const float*)d_in[1];
  const float* b1  = (const float*)d_in[2];
  const float* g1  = (const float*)d_in[3];
  const float* be1 = (const float*)d_in[4];
  const float* W2  = (const float*)d_in[5];
  const float* b2  = (const float*)d_in[6];
  const float* g2  = (const float*)d_in[7];
  const float* be2 = (const float*)d_in[8];
  const float* W3  = (const float*)d_in[9];
  const float* b3  = (const float*)d_in[10];
  const float* g3  = (const float*)d_in[11];
  const float* be3 = (const float*)d_in[12];

  char* ws = (char*)d_ws;
  ushort* h_raw    = (ushort*)(ws + 0);            // NHWC [8][65536][128]
  ushort* skip_raw = (ushort*)(ws + 134217728);    // NHWC [8][65536][128]
  ushort* dwt      = (ushort*)(ws + 268435456);    // NHWC [8][16384][512]
  ushort* in_nhwc  = (ushort*)(ws + 268435456);    // NHWC [8][65536][64] (aliased w/ dwt; dead before dwt written)
  ushort* raw3     = (ushort*)(ws + 402653184);    // NHWC [8][16384][128]
  float*  stats    = (float*)(ws + 436207616);
  float*  s1 = stats,          *q1 = stats + 4096;
  float*  s2 = stats + 8192,   *q2 = stats + 12288;
  float*  s3 = stats + 16384,  *q3 = stats + 20480;
  float*  coef = (float*)(ws + 436305920);
  float*  c1 = coef, *c2 = coef + 256, *c3 = coef + 512;
  ushort* Wp1 = (ushort*)(ws + 436308992);
  ushort* Wp2 = (ushort*)(ws + 436456448);
  ushort* Wp3 = (ushort*)(ws + 436751360);

  zero_f32<<<96, 256, 0, stream>>>(stats, 24576);
  pack_w<<<288, 256, 0, stream>>>(W1, Wp1, 64);
  pack_w<<<576, 256, 0, stream>>>(W2, Wp2, 128);
  pack_w<<<2304, 256, 0, stream>>>(W3, Wp3, 512);
  nchw2nhwc<<<dim3(1024, 8), 256, 0, stream>>>(input, in_nhwc);

  conv_dma<<<dim3(4, 128, 8), 256, 0, stream>>>(in_nhwc, Wp1, b1,
                                                h_raw, s1, q1, 64, 256, 256);
  bn_finalize<<<1, 128, 0, stream>>>(s1, q1, g1, be1, c1, 1.f / 524288.f);

  conv_reg<1><<<dim3(4, 128, 8), 256, 0, stream>>>(h_raw, Wp2, b2, c1,
                                                   skip_raw, s2, q2, 128, 256, 256);
  bn_finalize<<<1, 128, 0, stream>>>(s2, q2, g2, be2, c2, 1.f / 524288.f);

  skip_dwt2<<<dim3(4, 128, 32), 256, 0, stream>>>(skip_raw, c2, (float*)d_out, dwt);

  conv_dma<<<dim3(2, 64, 8), 256, 0, stream>>>(dwt, Wp3, b3,
                                               raw3, s3, q3, 512, 128, 128);
  bn_finalize<<<1, 128, 0, stream>>>(s3, q3, g3, be3, c3, 1.f / 131072.f);

  bn_transpose_out<<<dim3(2, 128, 32), 256, 0, stream>>>(raw3, c3, (float*)d_out + 67108864, 128, 128);
}